// Round 1
// 1773.772 us; speedup vs baseline: 2.0441x; 2.0441x over previous
//
#include <hip/hip_runtime.h>
#include <hip/hip_bf16.h>

// ws byte layout (12,976,128 B — proven footprint, unchanged):
//   REG0/REG1: bf16 [64 b][1024 k] @ 0 / 131072 — ring regions 0,1 (zero-init)
//   XT:  bf16 [512][64] @ 262144  x transposed [t][b] (immutable)
//   BAR: @ 327680: leaf[i]=+i*128 | root=+16*128 | mail[w]=+(17+w)*128
//        (grid_bar used ONCE, epoch 0). R7: per-WG phase flags live at the
//        SAME mail lines, dword offset +1 (zero-init, untouched by grid_bar).
//   ZERO:@ 366592 (256 B zeros — B-frag source for z1 k>=512 quadrant)
//   WP/RING: @ 393216, 96 x 131072. init stages hi/lo weights (M1hi@+0,
//        M1lo@+2M, M2hi@+4M, M2lo@+8M); lstm_kernel loads them to REGISTERS
//        pre-loop, then the bytes become ring regions 2..97.
//
// R7 re-partition: WG = [16 b][64 cols] instead of [64 b][16 cols].
//   grid 256 = 4 independent b-groups (g=bx>>6) x 64 col-WGs (c=bx&63).
//   Rows of the ring are group-pure (row = 2048 B, line-aligned) -> the 4
//   groups never communicate after the pre-loop barrier. Per-CU A-ingest
//   drops 128 KB -> 32 KB/phase; the 3-hop grid barrier is replaced by a
//   group-local single-hop flag fan-in (store flag after h-drain; one wave
//   polls 64 flags, one per lane, each on its own 128-B line).
#define XT_B 262144
#define BAR_B 327680
#define ZERO_B 366592
#define WP_B 393216
#define M1HI_B (WP_B + 0)
#define M1LO_B (WP_B + 2097152)
#define M2HI_B (WP_B + 4194304)
#define M2LO_B (WP_B + 8388608)
#define NREG 98
#define REG_BYTES 131072
#define BAR_INTS (273 * 32)
// final h2 (step 511) written at phase 512 -> region 513%98 = 23 -> base:
#define FINAL_REG_B (WP_B + (23 - 2) * REG_BYTES)   // = 3,145,728

typedef __attribute__((ext_vector_type(4))) unsigned int uint4v;
typedef __attribute__((ext_vector_type(8))) short short8;     // 8 bf16 (4 VGPRs)
typedef __attribute__((ext_vector_type(4))) float f32x4;
union AF { uint4v u; short8 s; };

__device__ __forceinline__ float sigm(float x) { return 1.f / (1.f + __expf(-x)); }
__device__ __forceinline__ float tanh_f(float x) {
    float a = fabsf(x);
    float e = __expf(-2.f * a);
    float r = (1.f - e) / (1.f + e);
    return copysignf(r, x);
}
__device__ __forceinline__ float bf2f(unsigned int u) {
    union { unsigned int i; float f; } v; v.i = u << 16; return v.f;
}
__device__ __forceinline__ unsigned short f2bf(float f) {
    union { float f; unsigned int i; } v; v.f = f;
    unsigned int u = v.i + 0x7fffu + ((v.i >> 16) & 1u);   // RNE
    return (unsigned short)(u >> 16);
}
__device__ __forceinline__ int reg_off(int r) {
    return (r < 2) ? r * REG_BYTES : WP_B + (r - 2) * REG_BYTES;
}

__global__ void init_kernel(const float* __restrict__ x, const float* __restrict__ W0,
                            const float* __restrict__ W1, char* __restrict__ wsb) {
    unsigned int* Hz = (unsigned int*)wsb;                   // regions 0,1 = 65536 dwords
    unsigned short* XT = (unsigned short*)(wsb + XT_B);
    int* BAR = (int*)(wsb + BAR_B);
    unsigned int* ZP = (unsigned int*)(wsb + ZERO_B);
    unsigned short* M1h = (unsigned short*)(wsb + M1HI_B);
    unsigned short* M1l = (unsigned short*)(wsb + M1LO_B);
    unsigned short* M2h = (unsigned short*)(wsb + M2HI_B);
    unsigned short* M2l = (unsigned short*)(wsb + M2LO_B);
    int i = blockIdx.x * blockDim.x + threadIdx.x;
    int stride = gridDim.x * blockDim.x;
    for (int j = i; j < 65536; j += stride) Hz[j] = 0;
    for (int j = i; j < 32768; j += stride) {
        int p = j >> 6, b = j & 63;
        XT[j] = f2bf(x[b * 512 + p]);
    }
    for (int j = i; j < BAR_INTS; j += stride) BAR[j] = 0;
    for (int j = i; j < 64; j += stride) ZP[j] = 0;
    for (int j = i; j < 2048 * 512; j += stride) {           // M1: W0 recurrent rows 1..512
        int c = j >> 9, k = j & 511;
        float f = W0[(1 + k) * 2048 + c];
        unsigned short hi = f2bf(f);
        unsigned short lo = f2bf(f - bf2f(hi));
        M1h[c * 512 + k] = hi;  M1l[c * 512 + k] = lo;
    }
    for (int j = i; j < 2048 * 1024; j += stride) {          // M2: W1 full
        int c = j >> 10, k = j & 1023;
        float f = W1[k * 2048 + c];
        unsigned short hi = f2bf(f);
        unsigned short lo = f2bf(f - bf2f(hi));
        M2h[c * 1024 + k] = hi;  M2l[c * 1024 + k] = lo;
    }
}

// R6 fan-out barrier — used exactly once (epoch 0, weight-staging recycle gate).
__device__ __forceinline__ void grid_bar(int* bar, int epoch, int bx, int t) {
    __syncthreads();
    if (t < 64) {
        int* leaf = bar + (bx >> 4) * 32;
        int* root = bar + 16 * 32;
        int* mailbase = bar + 17 * 32;
        int target = 16 * (epoch + 1);
        int isB = 0;
        if (t == 0) {
            int old = __hip_atomic_fetch_add(leaf, 1, __ATOMIC_RELAXED, __HIP_MEMORY_SCOPE_AGENT);
            if (old == target - 1) {
                int ro = __hip_atomic_fetch_add(root, 1, __ATOMIC_RELAXED, __HIP_MEMORY_SCOPE_AGENT);
                if (ro == target - 1) isB = 1;
            }
        }
        isB = __builtin_amdgcn_readfirstlane(isB);
        if (isB) {
            #pragma unroll
            for (int r = 0; r < 4; ++r)
                __hip_atomic_store(mailbase + (r * 64 + t) * 32, epoch + 1,
                                   __ATOMIC_RELAXED, __HIP_MEMORY_SCOPE_AGENT);
        }
        if (t == 0) {
            int* my = mailbase + bx * 32;
            while (__hip_atomic_load(my, __ATOMIC_RELAXED, __HIP_MEMORY_SCOPE_AGENT) < epoch + 1)
                __builtin_amdgcn_s_sleep(1);
        }
    }
    __syncthreads();
}

__global__ __launch_bounds__(512) void lstm_kernel(char* __restrict__ wsb,
        const float* __restrict__ W0, const float* __restrict__ b0,
        const float* __restrict__ b1) {
    // red[wave 8][col-local 64][b16 pad 20]  (pad 20 -> <=2-way LDS banking)
    __shared__ float red[8 * 64 * 20];

    const int t = threadIdx.x, bx = blockIdx.x;
    const int lane = t & 63;
    const int w = __builtin_amdgcn_readfirstlane(t >> 6);    // wave id = K-slice owner
    const int n = lane & 15, q = lane >> 4;
    const int g = bx >> 6;                                   // b-group (independent!)
    const int c = bx & 63;                                   // col-group within group

    const unsigned short* XT = (const unsigned short*)(wsb + XT_B);
    int* BAR = (int*)(wsb + BAR_B);

    // ---- one-time B-frags: 64 cols/WG. col-local cl = nt*16+n:
    //      cl<32 -> z1 (layer0, gate gi=cl>>3, unit u=c*8+(cl&7), K=512 real),
    //      cl>=32 -> z2 (layer1, same sub-mapping, K=1024). hi+lo = exact fp32.
    short8 Bhi[4][4], Blo[4][4];
    {
        #pragma unroll
        for (int nt = 0; nt < 4; ++nt) {
            int cl = nt * 16 + n;
            int lsel = cl >> 5;
            int cl2 = cl & 31;
            int colb = (cl2 >> 3) * 512 + c * 8 + (cl2 & 7);
            #pragma unroll
            for (int s = 0; s < 4; ++s) {
                int k_loc = w * 128 + s * 32 + q * 8;
                const short8 *phi, *plo;
                if (lsel == 0) {
                    if (k_loc < 512) {
                        phi = (const short8*)(wsb + M1HI_B + (colb * 512 + k_loc) * 2);
                        plo = (const short8*)(wsb + M1LO_B + (colb * 512 + k_loc) * 2);
                    } else {
                        phi = (const short8*)(wsb + ZERO_B + q * 16);
                        plo = phi;
                    }
                } else {
                    phi = (const short8*)(wsb + M2HI_B + (colb * 1024 + k_loc) * 2);
                    plo = (const short8*)(wsb + M2LO_B + (colb * 1024 + k_loc) * 2);
                }
                Bhi[nt][s] = *phi;  Blo[nt][s] = *plo;
            }
        }
    }
    // Pin B-frags: staging bytes are recycled as ring regions after epoch 0.
    asm volatile("" : "+v"(Bhi[0][0]), "+v"(Bhi[0][1]), "+v"(Bhi[0][2]), "+v"(Bhi[0][3]),
                      "+v"(Bhi[1][0]), "+v"(Bhi[1][1]), "+v"(Bhi[1][2]), "+v"(Bhi[1][3]) :: "memory");
    asm volatile("" : "+v"(Bhi[2][0]), "+v"(Bhi[2][1]), "+v"(Bhi[2][2]), "+v"(Bhi[2][3]),
                      "+v"(Bhi[3][0]), "+v"(Bhi[3][1]), "+v"(Bhi[3][2]), "+v"(Bhi[3][3]) :: "memory");
    asm volatile("" : "+v"(Blo[0][0]), "+v"(Blo[0][1]), "+v"(Blo[0][2]), "+v"(Blo[0][3]),
                      "+v"(Blo[1][0]), "+v"(Blo[1][1]), "+v"(Blo[1][2]), "+v"(Blo[1][3]) :: "memory");
    asm volatile("" : "+v"(Blo[2][0]), "+v"(Blo[2][1]), "+v"(Blo[2][2]), "+v"(Blo[2][3]),
                      "+v"(Blo[3][0]), "+v"(Blo[3][1]), "+v"(Blo[3][2]), "+v"(Blo[3][3]) :: "memory");

    // ---- cell threads: t<256, 1 cell each: layer cl_l=t>>7, unit uu=(t>>4)&7,
    //      batch b16=t&15 (global b = g*16+b16).
    const int cl_l = t >> 7;
    const int uu = (t >> 4) & 7;
    const int b16 = t & 15;
    const int bglob = g * 16 + b16;
    float cs = 0.f;
    float bi = 0, bj_ = 0, bf_ = 0, bo_ = 0;
    float wxi = 0, wxj = 0, wxf = 0, wxo = 0;
    if (t < 256) {
        int u = c * 8 + uu;
        const float* bb = (cl_l == 0) ? b0 : b1;
        bi  = bb[u];         bj_ = bb[512 + u];
        bf_ = bb[1024 + u];  bo_ = bb[1536 + u];
        if (cl_l == 0) {
            wxi = W0[u];         wxj = W0[512 + u];
            wxf = W0[1024 + u];  wxo = W0[1536 + u];
        }
    }

    // Global pre-loop barrier (epoch 0): ALL 256 WGs consumed the weight bytes
    // before ANY group's phase-1 store recycles them. Groups go independent after.
    grid_bar(BAR, 0, bx, t);

    // A-frag per-lane byte offset: region row g*16 + n, K-slice (w,q).
    const int base_a = (g * 16 + n) * 2048 + w * 256 + q * 16;
    int* flg_store = BAR + (17 + (g << 6) + c) * 32 + 1;     // own flag (offset +1!)
    int* flg_poll  = BAR + (17 + (g << 6) + lane) * 32 + 1;  // one group-flag per lane

    int rd = 0;                       // read region = p % 98
    for (int p = 0; p <= 512; ++p) {
        const int wr = (rd + 1 == NREG) ? 0 : rd + 1;
        // ---- A-frags: PLAIN cached loads, 4 x dwordx4 per lane (16 rows only).
        const char* hb = wsb + reg_off(rd) + base_a;
        uint4v av[4];
        asm volatile(
            "global_load_dwordx4 %0, %4, off\n\t"
            "global_load_dwordx4 %1, %4, off offset:64\n\t"
            "global_load_dwordx4 %2, %4, off offset:128\n\t"
            "global_load_dwordx4 %3, %4, off offset:192\n\t"
            "s_waitcnt vmcnt(0)"
            : "=&v"(av[0]), "=&v"(av[1]), "=&v"(av[2]), "=&v"(av[3])
            : "v"(hb) : "memory");

        // ---- MFMA: [16 b x 64 c] partial over this wave's K=128 slice.
        //      Waves 4..7 skip z1 cols (nt<2): that quadrant is zeros.
        f32x4 acc[4];
        #pragma unroll
        for (int nt = 0; nt < 4; ++nt) acc[nt] = (f32x4){0.f, 0.f, 0.f, 0.f};
        #pragma unroll
        for (int s = 0; s < 4; ++s) {
            AF af; af.u = av[s];
            #pragma unroll
            for (int nt = 0; nt < 4; ++nt) {
                if (nt < 2 && w >= 4) continue;
                acc[nt] = __builtin_amdgcn_mfma_f32_16x16x32_bf16(af.s, Bhi[nt][s], acc[nt], 0, 0, 0);
                acc[nt] = __builtin_amdgcn_mfma_f32_16x16x32_bf16(af.s, Blo[nt][s], acc[nt], 0, 0, 0);
            }
        }
        // C layout: col = lane&15 -> cl = nt*16+n; rows b16 = q*4 + reg
        #pragma unroll
        for (int nt = 0; nt < 4; ++nt) {
            if (nt < 2 && w >= 4) continue;
            float* dst = red + (w * 64 + nt * 16 + n) * 20 + q * 4;
            *(f32x4*)dst = acc[nt];
        }
        float xv = (t < 128 && p < 512) ? bf2f((unsigned int)XT[p * 64 + bglob]) : 0.f;
        __syncthreads();
        // ---- cell update (t<256), publish h to MALL (ring region wr) ----
        if (t < 256) {
            bool active = (cl_l == 0) ? (p < 512) : (p >= 1);
            if (active) {
                float zi = bi, zj = bj_, zf = bf_, zo = bo_;
                const int cbase = cl_l * 32 + uu;            // gate gi adds +8 cols = +160 floats
                if (cl_l == 0) {                              // z1: K=512 lives in waves 0..3
                    #pragma unroll
                    for (int ww = 0; ww < 4; ++ww) {
                        const float* rp = red + (ww * 64 + cbase) * 20 + b16;
                        zi += rp[0]; zj += rp[160]; zf += rp[320]; zo += rp[480];
                    }
                    zi += xv * wxi; zj += xv * wxj; zf += xv * wxf; zo += xv * wxo;
                } else {                                      // z2: full K, 8 waves
                    #pragma unroll
                    for (int ww = 0; ww < 8; ++ww) {
                        const float* rp = red + (ww * 64 + cbase) * 20 + b16;
                        zi += rp[0]; zj += rp[160]; zf += rp[320]; zo += rp[480];
                    }
                }
                cs = cs * sigm(zf + 1.f) + sigm(zi) * tanh_f(zj);
                float h = tanh_f(cs) * sigm(zo);
                unsigned int hb16 = (unsigned int)f2bf(h);
                unsigned int ob = (unsigned int)__shfl_xor((int)hb16, 16, 64); // partner uu^1
                if ((uu & 1) == 0) {
                    unsigned int packed = hb16 | (ob << 16);
                    unsigned int* dst = (unsigned int*)(wsb + reg_off(wr))
                                      + bglob * 512 + cl_l * 256 + c * 4 + (uu >> 1);
                    __hip_atomic_store(dst, packed, __ATOMIC_RELAXED, __HIP_MEMORY_SCOPE_AGENT);
                }
            }
        }
        // ---- group-local single-hop barrier: drain h stores (vmcnt0 at the
        //      barrier), publish flag=p+1, one wave polls own group's 64 flags.
        __syncthreads();
        if (t == 0)
            __hip_atomic_store(flg_store, p + 1, __ATOMIC_RELAXED, __HIP_MEMORY_SCOPE_AGENT);
        if (t < 64) {
            while (__hip_atomic_load(flg_poll, __ATOMIC_RELAXED, __HIP_MEMORY_SCOPE_AGENT) < p + 1) { }
        }
        __syncthreads();
        rd = wr;
    }
}

__global__ void logits_kernel(const char* __restrict__ wsb, const float* __restrict__ sw,
                              const float* __restrict__ sb, float* __restrict__ out) {
    // final h2 = h2[511], written at phase 512 -> region 23, rows [b][512+k]
    const unsigned short* Hs = (const unsigned short*)(wsb + FINAL_REG_B);
    int c = blockIdx.x, b = threadIdx.x;
    float acc = 0.f;
    for (int k = 0; k < 512; ++k)
        acc += bf2f((unsigned int)Hs[b * 1024 + 512 + k]) * sw[k * 10 + c];
    out[b * 10 + c] = acc + sb[c];
}

extern "C" void kernel_launch(void* const* d_in, const int* in_sizes, int n_in,
                              void* d_out, int out_size, void* d_ws, size_t ws_size,
                              hipStream_t stream) {
    (void)in_sizes; (void)n_in; (void)out_size; (void)ws_size;
    const float* x  = (const float*)d_in[0];
    const float* W0 = (const float*)d_in[1];
    const float* b0 = (const float*)d_in[2];
    const float* W1 = (const float*)d_in[3];
    const float* b1 = (const float*)d_in[4];
    const float* sw = (const float*)d_in[5];
    const float* sb = (const float*)d_in[6];
    char* wsb  = (char*)d_ws;
    float* out = (float*)d_out;

    hipLaunchKernelGGL(init_kernel, dim3(1024), dim3(256), 0, stream, x, W0, W1, wsb);

    char* wsb_p = wsb;
    const float* W0_p = W0;
    const float* b0_p = b0;
    const float* b1_p = b1;
    void* args[] = { &wsb_p, &W0_p, &b0_p, &b1_p };
    (void)hipLaunchCooperativeKernel((void*)lstm_kernel, dim3(256), dim3(512), args, 0, stream);

    hipLaunchKernelGGL(logits_kernel, dim3(10), dim3(64), 0, stream, wsb, sw, sb, out);
}

// Round 3
// 1764.399 us; speedup vs baseline: 2.0549x; 1.0053x over previous
//
#include <hip/hip_runtime.h>
#include <hip/hip_bf16.h>

// ws byte layout (12,976,128 B — proven footprint, unchanged):
//   REG0/REG1: bf16 [64 b][1024 k] @ 0 / 131072 — ring regions 0,1 (zero-init)
//   XT:  bf16 [512][64] @ 262144  x transposed [t][b] (immutable)
//   BAR: @ 327680: leaf[i]=+i*128 | root=+16*128 | mail[w]=+(17+w)*128
//        (grid_bar used ONCE, epoch 0). Per-WG phase flags live at the
//        SAME mail lines, dword offset +1 (zero-init, untouched by grid_bar).
//   ZERO:@ 366592 (256 B zeros — B-frag source for z1 k>=512 quadrant)
//   WP/RING: @ 393216, 96 x 131072. init stages hi/lo weights (M1hi@+0,
//        M1lo@+2M, M2hi@+4M, M2lo@+8M); lstm_kernel loads them to REGISTERS
//        pre-loop, then the bytes become ring regions 2..97.
//
// R9 = R7 (proven passing, 1689 us) + __launch_bounds__(512, 2).
//   R7 compiled to VGPR_Count=108 (2 blocks/CU target) while holding ~200
//   live dwords/lane (128 of asm-pinned B-frags alone) -> ~90 dwords/lane
//   spilled to scratch, re-read EVERY phase (~184 KB/CU/phase of reload
//   traffic). Cooperative launch needs only 1 WG/CU (grid 256 = CU count),
//   so min-waves-per-EU=2 legalizes a 256-VGPR budget: B-frags stay resident.
//   Everything else is bit-identical to R7 (same arithmetic -> same absmax).
#define XT_B 262144
#define BAR_B 327680
#define ZERO_B 366592
#define WP_B 393216
#define M1HI_B (WP_B + 0)
#define M1LO_B (WP_B + 2097152)
#define M2HI_B (WP_B + 4194304)
#define M2LO_B (WP_B + 8388608)
#define NREG 98
#define REG_BYTES 131072
#define BAR_INTS (273 * 32)
// final h2 (step 511) written at phase 512 -> region 513%98 = 23 -> base:
#define FINAL_REG_B (WP_B + (23 - 2) * REG_BYTES)   // = 3,145,728

typedef __attribute__((ext_vector_type(4))) unsigned int uint4v;
typedef __attribute__((ext_vector_type(8))) short short8;     // 8 bf16 (4 VGPRs)
typedef __attribute__((ext_vector_type(4))) float f32x4;
union AF { uint4v u; short8 s; };

__device__ __forceinline__ float sigm(float x) { return 1.f / (1.f + __expf(-x)); }
__device__ __forceinline__ float tanh_f(float x) {
    float a = fabsf(x);
    float e = __expf(-2.f * a);
    float r = (1.f - e) / (1.f + e);
    return copysignf(r, x);
}
__device__ __forceinline__ float bf2f(unsigned int u) {
    union { unsigned int i; float f; } v; v.i = u << 16; return v.f;
}
__device__ __forceinline__ unsigned short f2bf(float f) {
    union { float f; unsigned int i; } v; v.f = f;
    unsigned int u = v.i + 0x7fffu + ((v.i >> 16) & 1u);   // RNE
    return (unsigned short)(u >> 16);
}
__device__ __forceinline__ int reg_off(int r) {
    return (r < 2) ? r * REG_BYTES : WP_B + (r - 2) * REG_BYTES;
}

__global__ void init_kernel(const float* __restrict__ x, const float* __restrict__ W0,
                            const float* __restrict__ W1, char* __restrict__ wsb) {
    unsigned int* Hz = (unsigned int*)wsb;                   // regions 0,1 = 65536 dwords
    unsigned short* XT = (unsigned short*)(wsb + XT_B);
    int* BAR = (int*)(wsb + BAR_B);
    unsigned int* ZP = (unsigned int*)(wsb + ZERO_B);
    unsigned short* M1h = (unsigned short*)(wsb + M1HI_B);
    unsigned short* M1l = (unsigned short*)(wsb + M1LO_B);
    unsigned short* M2h = (unsigned short*)(wsb + M2HI_B);
    unsigned short* M2l = (unsigned short*)(wsb + M2LO_B);
    int i = blockIdx.x * blockDim.x + threadIdx.x;
    int stride = gridDim.x * blockDim.x;
    for (int j = i; j < 65536; j += stride) Hz[j] = 0;
    for (int j = i; j < 32768; j += stride) {
        int p = j >> 6, b = j & 63;
        XT[j] = f2bf(x[b * 512 + p]);
    }
    for (int j = i; j < BAR_INTS; j += stride) BAR[j] = 0;
    for (int j = i; j < 64; j += stride) ZP[j] = 0;
    for (int j = i; j < 2048 * 512; j += stride) {           // M1: W0 recurrent rows 1..512
        int c = j >> 9, k = j & 511;
        float f = W0[(1 + k) * 2048 + c];
        unsigned short hi = f2bf(f);
        unsigned short lo = f2bf(f - bf2f(hi));
        M1h[c * 512 + k] = hi;  M1l[c * 512 + k] = lo;
    }
    for (int j = i; j < 2048 * 1024; j += stride) {          // M2: W1 full
        int c = j >> 10, k = j & 1023;
        float f = W1[k * 2048 + c];
        unsigned short hi = f2bf(f);
        unsigned short lo = f2bf(f - bf2f(hi));
        M2h[c * 1024 + k] = hi;  M2l[c * 1024 + k] = lo;
    }
}

// R6 fan-out barrier — used exactly once (epoch 0, weight-staging recycle gate).
__device__ __forceinline__ void grid_bar(int* bar, int epoch, int bx, int t) {
    __syncthreads();
    if (t < 64) {
        int* leaf = bar + (bx >> 4) * 32;
        int* root = bar + 16 * 32;
        int* mailbase = bar + 17 * 32;
        int target = 16 * (epoch + 1);
        int isB = 0;
        if (t == 0) {
            int old = __hip_atomic_fetch_add(leaf, 1, __ATOMIC_RELAXED, __HIP_MEMORY_SCOPE_AGENT);
            if (old == target - 1) {
                int ro = __hip_atomic_fetch_add(root, 1, __ATOMIC_RELAXED, __HIP_MEMORY_SCOPE_AGENT);
                if (ro == target - 1) isB = 1;
            }
        }
        isB = __builtin_amdgcn_readfirstlane(isB);
        if (isB) {
            #pragma unroll
            for (int r = 0; r < 4; ++r)
                __hip_atomic_store(mailbase + (r * 64 + t) * 32, epoch + 1,
                                   __ATOMIC_RELAXED, __HIP_MEMORY_SCOPE_AGENT);
        }
        if (t == 0) {
            int* my = mailbase + bx * 32;
            while (__hip_atomic_load(my, __ATOMIC_RELAXED, __HIP_MEMORY_SCOPE_AGENT) < epoch + 1)
                __builtin_amdgcn_s_sleep(1);
        }
    }
    __syncthreads();
}

__global__ __launch_bounds__(512, 2) void lstm_kernel(char* __restrict__ wsb,
        const float* __restrict__ W0, const float* __restrict__ b0,
        const float* __restrict__ b1) {
    // red[wave 8][col-local 64][b16 pad 20]
    __shared__ float red[8 * 64 * 20];

    const int t = threadIdx.x, bx = blockIdx.x;
    const int lane = t & 63;
    const int w = __builtin_amdgcn_readfirstlane(t >> 6);    // wave id = K-slice owner
    const int n = lane & 15, q = lane >> 4;
    const int g = bx >> 6;                                   // b-group (independent!)
    const int c = bx & 63;                                   // col-group within group

    const unsigned short* XT = (const unsigned short*)(wsb + XT_B);
    int* BAR = (int*)(wsb + BAR_B);

    // ---- one-time B-frags: 64 cols/WG. col-local cl = nt*16+n:
    //      cl<32 -> z1 (layer0, gate gi=cl>>3, unit u=c*8+(cl&7), K=512 real),
    //      cl>=32 -> z2 (layer1, same sub-mapping, K=1024). hi+lo = exact fp32.
    short8 Bhi[4][4], Blo[4][4];
    {
        #pragma unroll
        for (int nt = 0; nt < 4; ++nt) {
            int cl = nt * 16 + n;
            int lsel = cl >> 5;
            int cl2 = cl & 31;
            int colb = (cl2 >> 3) * 512 + c * 8 + (cl2 & 7);
            #pragma unroll
            for (int s = 0; s < 4; ++s) {
                int k_loc = w * 128 + s * 32 + q * 8;
                const short8 *phi, *plo;
                if (lsel == 0) {
                    if (k_loc < 512) {
                        phi = (const short8*)(wsb + M1HI_B + (colb * 512 + k_loc) * 2);
                        plo = (const short8*)(wsb + M1LO_B + (colb * 512 + k_loc) * 2);
                    } else {
                        phi = (const short8*)(wsb + ZERO_B + q * 16);
                        plo = phi;
                    }
                } else {
                    phi = (const short8*)(wsb + M2HI_B + (colb * 1024 + k_loc) * 2);
                    plo = (const short8*)(wsb + M2LO_B + (colb * 1024 + k_loc) * 2);
                }
                Bhi[nt][s] = *phi;  Blo[nt][s] = *plo;
            }
        }
    }
    // Pin B-frags: staging bytes are recycled as ring regions after epoch 0.
    asm volatile("" : "+v"(Bhi[0][0]), "+v"(Bhi[0][1]), "+v"(Bhi[0][2]), "+v"(Bhi[0][3]),
                      "+v"(Bhi[1][0]), "+v"(Bhi[1][1]), "+v"(Bhi[1][2]), "+v"(Bhi[1][3]) :: "memory");
    asm volatile("" : "+v"(Bhi[2][0]), "+v"(Bhi[2][1]), "+v"(Bhi[2][2]), "+v"(Bhi[2][3]),
                      "+v"(Bhi[3][0]), "+v"(Bhi[3][1]), "+v"(Bhi[3][2]), "+v"(Bhi[3][3]) :: "memory");
    asm volatile("" : "+v"(Blo[0][0]), "+v"(Blo[0][1]), "+v"(Blo[0][2]), "+v"(Blo[0][3]),
                      "+v"(Blo[1][0]), "+v"(Blo[1][1]), "+v"(Blo[1][2]), "+v"(Blo[1][3]) :: "memory");
    asm volatile("" : "+v"(Blo[2][0]), "+v"(Blo[2][1]), "+v"(Blo[2][2]), "+v"(Blo[2][3]),
                      "+v"(Blo[3][0]), "+v"(Blo[3][1]), "+v"(Blo[3][2]), "+v"(Blo[3][3]) :: "memory");

    // ---- cell threads: t<256, 1 cell each: layer cl_l=t>>7, unit uu=(t>>4)&7,
    //      batch b16=t&15 (global b = g*16+b16).
    const int cl_l = t >> 7;
    const int uu = (t >> 4) & 7;
    const int b16 = t & 15;
    const int bglob = g * 16 + b16;
    float cs = 0.f;
    float bi = 0, bj_ = 0, bf_ = 0, bo_ = 0;
    float wxi = 0, wxj = 0, wxf = 0, wxo = 0;
    if (t < 256) {
        int u = c * 8 + uu;
        const float* bb = (cl_l == 0) ? b0 : b1;
        bi  = bb[u];         bj_ = bb[512 + u];
        bf_ = bb[1024 + u];  bo_ = bb[1536 + u];
        if (cl_l == 0) {
            wxi = W0[u];         wxj = W0[512 + u];
            wxf = W0[1024 + u];  wxo = W0[1536 + u];
        }
    }

    // Global pre-loop barrier (epoch 0): ALL 256 WGs consumed the weight bytes
    // before ANY group's phase-1 store recycles them. Groups go independent after.
    grid_bar(BAR, 0, bx, t);

    // A-frag per-lane byte offset: region row g*16 + n, K-slice (w,q).
    const int base_a = (g * 16 + n) * 2048 + w * 256 + q * 16;
    int* flg_store = BAR + (17 + (g << 6) + c) * 32 + 1;     // own flag (offset +1!)
    int* flg_poll  = BAR + (17 + (g << 6) + lane) * 32 + 1;  // one group-flag per lane

    int rd = 0;                       // read region = p % 98
    for (int p = 0; p <= 512; ++p) {
        const int wr = (rd + 1 == NREG) ? 0 : rd + 1;
        // ---- A-frags: PLAIN cached loads, 4 x dwordx4 per lane (16 rows only).
        const char* hb = wsb + reg_off(rd) + base_a;
        uint4v av[4];
        asm volatile(
            "global_load_dwordx4 %0, %4, off\n\t"
            "global_load_dwordx4 %1, %4, off offset:64\n\t"
            "global_load_dwordx4 %2, %4, off offset:128\n\t"
            "global_load_dwordx4 %3, %4, off offset:192\n\t"
            "s_waitcnt vmcnt(0)"
            : "=&v"(av[0]), "=&v"(av[1]), "=&v"(av[2]), "=&v"(av[3])
            : "v"(hb) : "memory");

        // ---- MFMA: [16 b x 64 c] partial over this wave's K=128 slice.
        //      Waves 4..7 skip z1 cols (nt<2): that quadrant is zeros.
        f32x4 acc[4];
        #pragma unroll
        for (int nt = 0; nt < 4; ++nt) acc[nt] = (f32x4){0.f, 0.f, 0.f, 0.f};
        #pragma unroll
        for (int s = 0; s < 4; ++s) {
            AF af; af.u = av[s];
            #pragma unroll
            for (int nt = 0; nt < 4; ++nt) {
                if (nt < 2 && w >= 4) continue;
                acc[nt] = __builtin_amdgcn_mfma_f32_16x16x32_bf16(af.s, Bhi[nt][s], acc[nt], 0, 0, 0);
                acc[nt] = __builtin_amdgcn_mfma_f32_16x16x32_bf16(af.s, Blo[nt][s], acc[nt], 0, 0, 0);
            }
        }
        // C layout: col = lane&15 -> cl = nt*16+n; rows b16 = q*4 + reg
        #pragma unroll
        for (int nt = 0; nt < 4; ++nt) {
            if (nt < 2 && w >= 4) continue;
            float* dst = red + (w * 64 + nt * 16 + n) * 20 + q * 4;
            *(f32x4*)dst = acc[nt];
        }
        float xv = (t < 128 && p < 512) ? bf2f((unsigned int)XT[p * 64 + bglob]) : 0.f;
        __syncthreads();
        // ---- cell update (t<256), publish h to MALL (ring region wr) ----
        if (t < 256) {
            bool active = (cl_l == 0) ? (p < 512) : (p >= 1);
            if (active) {
                float zi = bi, zj = bj_, zf = bf_, zo = bo_;
                const int cbase = cl_l * 32 + uu;            // gate gi adds +8 cols = +160 floats
                if (cl_l == 0) {                              // z1: K=512 lives in waves 0..3
                    #pragma unroll
                    for (int ww = 0; ww < 4; ++ww) {
                        const float* rp = red + (ww * 64 + cbase) * 20 + b16;
                        zi += rp[0]; zj += rp[160]; zf += rp[320]; zo += rp[480];
                    }
                    zi += xv * wxi; zj += xv * wxj; zf += xv * wxf; zo += xv * wxo;
                } else {                                      // z2: full K, 8 waves
                    #pragma unroll
                    for (int ww = 0; ww < 8; ++ww) {
                        const float* rp = red + (ww * 64 + cbase) * 20 + b16;
                        zi += rp[0]; zj += rp[160]; zf += rp[320]; zo += rp[480];
                    }
                }
                cs = cs * sigm(zf + 1.f) + sigm(zi) * tanh_f(zj);
                float h = tanh_f(cs) * sigm(zo);
                unsigned int hb16 = (unsigned int)f2bf(h);
                unsigned int ob = (unsigned int)__shfl_xor((int)hb16, 16, 64); // partner uu^1
                if ((uu & 1) == 0) {
                    unsigned int packed = hb16 | (ob << 16);
                    unsigned int* dst = (unsigned int*)(wsb + reg_off(wr))
                                      + bglob * 512 + cl_l * 256 + c * 4 + (uu >> 1);
                    __hip_atomic_store(dst, packed, __ATOMIC_RELAXED, __HIP_MEMORY_SCOPE_AGENT);
                }
            }
        }
        // ---- group-local single-hop barrier: drain h stores (vmcnt0 at the
        //      barrier), publish flag=p+1, one wave polls own group's 64 flags.
        __syncthreads();
        if (t == 0)
            __hip_atomic_store(flg_store, p + 1, __ATOMIC_RELAXED, __HIP_MEMORY_SCOPE_AGENT);
        if (t < 64) {
            while (__hip_atomic_load(flg_poll, __ATOMIC_RELAXED, __HIP_MEMORY_SCOPE_AGENT) < p + 1) { }
        }
        __syncthreads();
        rd = wr;
    }
}

__global__ void logits_kernel(const char* __restrict__ wsb, const float* __restrict__ sw,
                              const float* __restrict__ sb, float* __restrict__ out) {
    // final h2 = h2[511], written at phase 512 -> region 23, rows [b][512+k]
    const unsigned short* Hs = (const unsigned short*)(wsb + FINAL_REG_B);
    int c = blockIdx.x, b = threadIdx.x;
    float acc = 0.f;
    for (int k = 0; k < 512; ++k)
        acc += bf2f((unsigned int)Hs[b * 1024 + 512 + k]) * sw[k * 10 + c];
    out[b * 10 + c] = acc + sb[c];
}

extern "C" void kernel_launch(void* const* d_in, const int* in_sizes, int n_in,
                              void* d_out, int out_size, void* d_ws, size_t ws_size,
                              hipStream_t stream) {
    (void)in_sizes; (void)n_in; (void)out_size; (void)ws_size;
    const float* x  = (const float*)d_in[0];
    const float* W0 = (const float*)d_in[1];
    const float* b0 = (const float*)d_in[2];
    const float* W1 = (const float*)d_in[3];
    const float* b1 = (const float*)d_in[4];
    const float* sw = (const float*)d_in[5];
    const float* sb = (const float*)d_in[6];
    char* wsb  = (char*)d_ws;
    float* out = (float*)d_out;

    hipLaunchKernelGGL(init_kernel, dim3(1024), dim3(256), 0, stream, x, W0, W1, wsb);

    char* wsb_p = wsb;
    const float* W0_p = W0;
    const float* b0_p = b0;
    const float* b1_p = b1;
    void* args[] = { &wsb_p, &W0_p, &b0_p, &b1_p };
    (void)hipLaunchCooperativeKernel((void*)lstm_kernel, dim3(256), dim3(512), args, 0, stream);

    hipLaunchKernelGGL(logits_kernel, dim3(10), dim3(64), 0, stream, wsb, sw, sb, out);
}